// Round 1
// baseline (329.143 us; speedup 1.0000x reference)
//
#include <hip/hip_runtime.h>
#include <hip/hip_bf16.h>

// ConvIntrinsic: gather+barycentric -> patch-operator -> 8 rotated folds.
// Restructured as: sig (N x 5120 bf16), W2 (2048 x 5120 bf16, interp folded
// into kernel_weights per rotation), one bf16 MFMA GEMM (M=6000,N=2048,K=5120)
// with fused bias+relu+k-pair-sum epilogue.
//
// N=6000 R=5 A=8 F=128 K=2 O=128; out (6000, 8, 128) f32.
// Column order j = rot*256 + o*2 + k  -> relu pair (k=0/1) sits in adjacent
// lanes of the MFMA C fragment (col = lane&15) -> __shfl_xor pair-sum.

#define N_PTS 6000
#define RR 5
#define AA 8
#define FF 128
#define OO 128
#define QQ 40          // R*A
#define KD 5120        // QQ*FF  (GEMM K)
#define NCOL 2048      // 8 rot * 2 k * 128 o (GEMM N)

typedef __bf16 bf16_t;
typedef __bf16 bf16x8 __attribute__((ext_vector_type(8)));
typedef float f32x4 __attribute__((ext_vector_type(4)));

#define GLOAD_LDS16(g, l)                                              \
  __builtin_amdgcn_global_load_lds(                                    \
      (const __attribute__((address_space(1))) void*)(g),              \
      (__attribute__((address_space(3))) void*)(l), 16, 0, 0)

// ---------------------------------------------------------------- sig pass
// sig[n, q*128+f] = sum_j w[n,q,j] * mesh[idx[n,q,j], f]   (bf16 out)
__global__ __launch_bounds__(256) void sig_kernel(
    const float* __restrict__ mesh, const float* __restrict__ bary,
    bf16_t* __restrict__ sig) {
  const int n = blockIdx.x;
  const int f = threadIdx.x & 127;
  const int qh = threadIdx.x >> 7;  // two q's in flight per block
  const float* bn = bary + (size_t)n * (QQ * 6);
  bf16_t* sn = sig + (size_t)n * KD;
  for (int qb = 0; qb < QQ / 2; ++qb) {
    const int q = qb * 2 + qh;
    const float* b = bn + q * 6;        // [i0,w0,i1,w1,i2,w2]
    const int i0 = (int)b[0]; const float w0 = b[1];
    const int i1 = (int)b[2]; const float w1 = b[3];
    const int i2 = (int)b[4]; const float w2 = b[5];
    const float v = w0 * mesh[(size_t)i0 * FF + f] +
                    w1 * mesh[(size_t)i1 * FF + f] +
                    w2 * mesh[(size_t)i2 * FF + f];
    sn[q * FF + f] = (bf16_t)v;
  }
}

// ---------------------------------------------------------------- W2 pass
// Bt[j, q*128+f] = sum_{r,a'} interp[r,a',q] * kw[r,(a'+rot)&7,k,o,f]
// j = rot*256 + o*2 + k.  One block per j, 128 threads (f).
__global__ __launch_bounds__(128) void w2_kernel(
    const float* __restrict__ kw, const float* __restrict__ interp,
    bf16_t* __restrict__ Bt) {
  __shared__ float sI[RR * AA * QQ];  // 1600 floats
  const int j = blockIdx.x;
  const int f = threadIdx.x;
  for (int i = f; i < RR * AA * QQ; i += 128) sI[i] = interp[i];
  __syncthreads();
  const int rot = j >> 8;
  const int o = (j >> 1) & 127;
  const int k = j & 1;
  float acc[QQ];
#pragma unroll
  for (int q = 0; q < QQ; ++q) acc[q] = 0.f;
  for (int r = 0; r < RR; ++r) {
    for (int a = 0; a < AA; ++a) {
      const int a2 = (a + rot) & 7;
      const float kv =
          kw[((size_t)((r * AA + a2) * 2 + k) * OO + o) * FF + f];
      const float4* ip = (const float4*)(sI + (r * AA + a) * QQ);
#pragma unroll
      for (int q4 = 0; q4 < QQ / 4; ++q4) {
        const float4 w4 = ip[q4];
        acc[q4 * 4 + 0] += w4.x * kv;
        acc[q4 * 4 + 1] += w4.y * kv;
        acc[q4 * 4 + 2] += w4.z * kv;
        acc[q4 * 4 + 3] += w4.w * kv;
      }
    }
  }
  bf16_t* bj = Bt + (size_t)j * KD;
#pragma unroll
  for (int q = 0; q < QQ; ++q) bj[q * FF + f] = (bf16_t)acc[q];
}

// ---------------------------------------------------------------- GEMM
// C[m,j] = sum_k sig[m,k]*Bt[j,k]; 128x128 tile, BK=64, 4 waves x 4x4 MFMA
// 16x16x32 bf16. global_load_lds width=16 staging; XOR k-chunk swizzle so
// ds_read_b128 fragment reads are bank-conflict-free (2-way only).
// Epilogue: v=relu(acc+40*bias[k,o]); out[m,rot*128+o] = v + shfl_xor(v,1).
__global__ __launch_bounds__(256) void gemm_kernel(
    const bf16_t* __restrict__ Asig, const bf16_t* __restrict__ Bt,
    const float* __restrict__ bias, float* __restrict__ out) {
  __shared__ bf16_t As[128 * 64];
  __shared__ bf16_t Bs[128 * 64];
  const int tid = threadIdx.x;
  const int wave = tid >> 6;
  const int lane = tid & 63;
  const int quad = lane >> 4;
  const int tl = lane & 15;
  const int wm = (wave & 1) * 64;
  const int wn = (wave >> 1) * 64;
  const int m0 = blockIdx.y * 128;
  const int n0 = blockIdx.x * 128;

  const int srow = lane >> 3;           // 0..7 row within 8-row chunk
  const int sc = (lane & 7) ^ srow;     // swizzled global k-chunk

  f32x4 acc[4][4];
#pragma unroll
  for (int mm = 0; mm < 4; ++mm)
#pragma unroll
    for (int nn = 0; nn < 4; ++nn) acc[mm][nn] = {0.f, 0.f, 0.f, 0.f};

  for (int kk = 0; kk < KD; kk += 64) {
    __syncthreads();
#pragma unroll
    for (int i = 0; i < 4; ++i) {
      const int row = wave * 32 + i * 8;      // wave-uniform LDS chunk base
      int gm = m0 + row + srow;
      gm = gm < N_PTS ? gm : (N_PTS - 1);     // clamp tail rows (masked later)
      const int gn = n0 + row + srow;
      GLOAD_LDS16(Asig + (size_t)gm * KD + kk + sc * 8, As + row * 64);
      GLOAD_LDS16(Bt + (size_t)gn * KD + kk + sc * 8, Bs + row * 64);
    }
    __syncthreads();
#pragma unroll
    for (int ks = 0; ks < 2; ++ks) {
      const int ch = (((ks * 4 + quad) ^ (tl & 7)) * 8);
      bf16x8 af[4], bfr[4];
#pragma unroll
      for (int mm = 0; mm < 4; ++mm)
        af[mm] = *(const bf16x8*)(As + (wm + mm * 16 + tl) * 64 + ch);
#pragma unroll
      for (int nn = 0; nn < 4; ++nn)
        bfr[nn] = *(const bf16x8*)(Bs + (wn + nn * 16 + tl) * 64 + ch);
#pragma unroll
      for (int mm = 0; mm < 4; ++mm)
#pragma unroll
        for (int nn = 0; nn < 4; ++nn)
          acc[mm][nn] = __builtin_amdgcn_mfma_f32_16x16x32_bf16(
              af[mm], bfr[nn], acc[mm][nn], 0, 0, 0);
    }
  }

  // epilogue: C/D layout col=lane&15, row=quad*4+reg (m89/m91-verified)
#pragma unroll
  for (int nn = 0; nn < 4; ++nn) {
    const int j = n0 + wn + nn * 16 + tl;
    const int half = j >> 1;  // rot*128 + o
    const float bb = 40.0f * bias[((j & 1) << 7) | (half & 127)];
#pragma unroll
    for (int mm = 0; mm < 4; ++mm) {
      const int mrow = m0 + wm + mm * 16 + quad * 4;
      const f32x4 a = acc[mm][nn];
#pragma unroll
      for (int r = 0; r < 4; ++r) {
        float v = a[r] + bb;
        v = v > 0.f ? v : 0.f;
        const float vs = v + __shfl_xor(v, 1, 64);
        if (((lane & 1) == 0) && (mrow + r < N_PTS))
          out[(size_t)(mrow + r) * (AA * OO) + half] = vs;
      }
    }
  }
}

extern "C" void kernel_launch(void* const* d_in, const int* in_sizes, int n_in,
                              void* d_out, int out_size, void* d_ws,
                              size_t ws_size, hipStream_t stream) {
  const float* mesh = (const float*)d_in[0];    // (6000,128)
  const float* bary = (const float*)d_in[1];    // (6000,5,8,3,2)
  const float* kw = (const float*)d_in[2];      // (5,8,2,128,128)
  const float* bias = (const float*)d_in[3];    // (2,128)
  const float* interp = (const float*)d_in[4];  // (5,8,40)
  float* out = (float*)d_out;                   // (6000,8,128)

  bf16_t* sig = (bf16_t*)d_ws;                                   // 61.44 MB
  bf16_t* Bt = (bf16_t*)((char*)d_ws + (size_t)N_PTS * KD * 2);  // 20.97 MB

  sig_kernel<<<N_PTS, 256, 0, stream>>>(mesh, bary, sig);
  w2_kernel<<<NCOL, 128, 0, stream>>>(kw, interp, Bt);
  gemm_kernel<<<dim3(16, 47), 256, 0, stream>>>(sig, Bt, bias, out);
}

// Round 2
// 308.169 us; speedup vs baseline: 1.0681x; 1.0681x over previous
//
#include <hip/hip_runtime.h>
#include <hip/hip_bf16.h>

// ConvIntrinsic: gather+barycentric -> patch-operator -> 8 rotated folds.
// sig (N x 5120 bf16), W2 (2048 x 5120 bf16, interp folded into
// kernel_weights per rotation), one bf16 MFMA GEMM (M=6000,N=2048,K=5120)
// with fused bias+relu+k-pair-sum epilogue.
//
// R2: XCD-aware GEMM block swizzle (16 same-A blocks -> one XCD's L2);
//     sig rewritten loop-free (float4 gathers, bf16x4 stores);
//     sig+w2 fused into one prep kernel (mem-bound + VALU-bound overlap).

#define N_PTS 6000
#define RR 5
#define AA 8
#define FF 128
#define OO 128
#define QQ 40          // R*A
#define KD 5120        // QQ*FF  (GEMM K)
#define NCOL 2048      // 8 rot * 2 k * 128 o (GEMM N)
#define SIG_BLOCKS (N_PTS * 5)   // 5 q-chunks of 8 per point
#define W2_BLOCKS (NCOL / 2)     // 2 j per block

typedef __bf16 bf16_t;
typedef __bf16 bf16x4 __attribute__((ext_vector_type(4)));
typedef __bf16 bf16x8 __attribute__((ext_vector_type(8)));
typedef float f32x4 __attribute__((ext_vector_type(4)));

#define GLOAD_LDS16(g, l)                                              \
  __builtin_amdgcn_global_load_lds(                                    \
      (const __attribute__((address_space(1))) void*)(g),              \
      (__attribute__((address_space(3))) void*)(l), 16, 0, 0)

// ------------------------------------------------------------- prep pass
// blocks [0, SIG_BLOCKS):       sig[n, q*128+f] = sum_j w * mesh[idx, f]
// blocks [SIG_BLOCKS, +W2):     Bt[j, q*128+f] = sum_ra interp*kw(rot-rolled)
__global__ __launch_bounds__(256) void prep_kernel(
    const float* __restrict__ mesh, const float* __restrict__ bary,
    const float* __restrict__ kw, const float* __restrict__ interp,
    bf16_t* __restrict__ sig, bf16_t* __restrict__ Bt) {
  __shared__ float sI[RR * AA * QQ];  // 1600 floats (w2 branch only)
  const int bx = blockIdx.x;
  const int tid = threadIdx.x;

  if (bx < SIG_BLOCKS) {
    // ---- sig: one (n, 8-q chunk) per block; 32 lanes x float4 over f.
    const int n = bx / 5;
    const int qb = bx - n * 5;
    const int qi = tid >> 5;        // 0..7
    const int l = tid & 31;         // f = l*4
    const int q = qb * 8 + qi;
    const float* b = bary + (size_t)n * (QQ * 6) + q * 6;
    const float2 p0 = *(const float2*)(b);
    const float2 p1 = *(const float2*)(b + 2);
    const float2 p2 = *(const float2*)(b + 4);
    const int i0 = (int)p0.x; const float w0 = p0.y;
    const int i1 = (int)p1.x; const float w1 = p1.y;
    const int i2 = (int)p2.x; const float w2 = p2.y;
    const float4 v0 = *(const float4*)(mesh + (size_t)i0 * FF + l * 4);
    const float4 v1 = *(const float4*)(mesh + (size_t)i1 * FF + l * 4);
    const float4 v2 = *(const float4*)(mesh + (size_t)i2 * FF + l * 4);
    bf16x4 o;
    o[0] = (bf16_t)(w0 * v0.x + w1 * v1.x + w2 * v2.x);
    o[1] = (bf16_t)(w0 * v0.y + w1 * v1.y + w2 * v2.y);
    o[2] = (bf16_t)(w0 * v0.z + w1 * v1.z + w2 * v2.z);
    o[3] = (bf16_t)(w0 * v0.w + w1 * v1.w + w2 * v2.w);
    *(bf16x4*)(sig + (size_t)n * KD + q * FF + l * 4) = o;
  } else {
    // ---- w2: two j columns per block (128 threads each).
    const int j = (bx - SIG_BLOCKS) * 2 + (tid >> 7);
    const int f = tid & 127;
    for (int i = tid; i < RR * AA * QQ; i += 256) sI[i] = interp[i];
    __syncthreads();
    const int rot = j >> 8;
    const int o = (j >> 1) & 127;
    const int k = j & 1;
    float acc[QQ];
#pragma unroll
    for (int q = 0; q < QQ; ++q) acc[q] = 0.f;
    for (int r = 0; r < RR; ++r) {
      for (int a = 0; a < AA; ++a) {
        const int a2 = (a + rot) & 7;
        const float kv =
            kw[((size_t)((r * AA + a2) * 2 + k) * OO + o) * FF + f];
        const float4* ip = (const float4*)(sI + (r * AA + a) * QQ);
#pragma unroll
        for (int q4 = 0; q4 < QQ / 4; ++q4) {
          const float4 w4 = ip[q4];
          acc[q4 * 4 + 0] += w4.x * kv;
          acc[q4 * 4 + 1] += w4.y * kv;
          acc[q4 * 4 + 2] += w4.z * kv;
          acc[q4 * 4 + 3] += w4.w * kv;
        }
      }
    }
    bf16_t* bj = Bt + (size_t)j * KD;
#pragma unroll
    for (int q = 0; q < QQ; ++q) bj[q * FF + f] = (bf16_t)acc[q];
  }
}

// ---------------------------------------------------------------- GEMM
// C[m,j] = sum_k sig[m,k]*Bt[j,k]; 128x128 tile, BK=64, 4 waves x 4x4 MFMA
// 16x16x32 bf16, global_load_lds width=16, XOR bank swizzle.
// Grid: 768 1D blocks; XCD-aware mapping — all 16 n-blocks of one m-row land
// on one XCD so the shared A-tile stays in that XCD's L2 (16x reuse).
// Epilogue: v=relu(acc+40*bias[k,o]); out[m,rot*128+o] = v + shfl_xor(v,1).
__global__ __launch_bounds__(256) void gemm_kernel(
    const bf16_t* __restrict__ Asig, const bf16_t* __restrict__ Bt,
    const float* __restrict__ bias, float* __restrict__ out) {
  __shared__ bf16_t As[128 * 64];
  __shared__ bf16_t Bs[128 * 64];
  const int L = blockIdx.x;
  const int xcd = L & 7;
  const int s = L >> 3;            // 0..95
  const int my = xcd + 8 * (s >> 4);  // 0..47
  const int nx = s & 15;
  const int m0 = my * 128;
  const int n0 = nx * 128;
  if (m0 >= N_PTS) return;         // my==47 pad block

  const int tid = threadIdx.x;
  const int wave = tid >> 6;
  const int lane = tid & 63;
  const int quad = lane >> 4;
  const int tl = lane & 15;
  const int wm = (wave & 1) * 64;
  const int wn = (wave >> 1) * 64;

  const int srow = lane >> 3;           // 0..7 row within 8-row chunk
  const int sc = (lane & 7) ^ srow;     // swizzled global k-chunk

  f32x4 acc[4][4];
#pragma unroll
  for (int mm = 0; mm < 4; ++mm)
#pragma unroll
    for (int nn = 0; nn < 4; ++nn) acc[mm][nn] = {0.f, 0.f, 0.f, 0.f};

  for (int kk = 0; kk < KD; kk += 64) {
    __syncthreads();
#pragma unroll
    for (int i = 0; i < 4; ++i) {
      const int row = wave * 32 + i * 8;      // wave-uniform LDS chunk base
      int gm = m0 + row + srow;
      gm = gm < N_PTS ? gm : (N_PTS - 1);     // clamp tail rows (masked later)
      const int gn = n0 + row + srow;
      GLOAD_LDS16(Asig + (size_t)gm * KD + kk + sc * 8, As + row * 64);
      GLOAD_LDS16(Bt + (size_t)gn * KD + kk + sc * 8, Bs + row * 64);
    }
    __syncthreads();
#pragma unroll
    for (int ks = 0; ks < 2; ++ks) {
      const int ch = (((ks * 4 + quad) ^ (tl & 7)) * 8);
      bf16x8 af[4], bfr[4];
#pragma unroll
      for (int mm = 0; mm < 4; ++mm)
        af[mm] = *(const bf16x8*)(As + (wm + mm * 16 + tl) * 64 + ch);
#pragma unroll
      for (int nn = 0; nn < 4; ++nn)
        bfr[nn] = *(const bf16x8*)(Bs + (wn + nn * 16 + tl) * 64 + ch);
#pragma unroll
      for (int mm = 0; mm < 4; ++mm)
#pragma unroll
        for (int nn = 0; nn < 4; ++nn)
          acc[mm][nn] = __builtin_amdgcn_mfma_f32_16x16x32_bf16(
              af[mm], bfr[nn], acc[mm][nn], 0, 0, 0);
    }
  }

  // epilogue: C/D layout col=lane&15, row=quad*4+reg (m89/m91-verified)
#pragma unroll
  for (int nn = 0; nn < 4; ++nn) {
    const int j = n0 + wn + nn * 16 + tl;
    const int half = j >> 1;  // rot*128 + o
    const float bb = 40.0f * bias[((j & 1) << 7) | (half & 127)];
#pragma unroll
    for (int mm = 0; mm < 4; ++mm) {
      const int mrow = m0 + wm + mm * 16 + quad * 4;
      const f32x4 a = acc[mm][nn];
#pragma unroll
      for (int r = 0; r < 4; ++r) {
        float v = a[r] + bb;
        v = v > 0.f ? v : 0.f;
        const float vs = v + __shfl_xor(v, 1, 64);
        if (((lane & 1) == 0) && (mrow + r < N_PTS))
          out[(size_t)(mrow + r) * (AA * OO) + half] = vs;
      }
    }
  }
}

extern "C" void kernel_launch(void* const* d_in, const int* in_sizes, int n_in,
                              void* d_out, int out_size, void* d_ws,
                              size_t ws_size, hipStream_t stream) {
  const float* mesh = (const float*)d_in[0];    // (6000,128)
  const float* bary = (const float*)d_in[1];    // (6000,5,8,3,2)
  const float* kw = (const float*)d_in[2];      // (5,8,2,128,128)
  const float* bias = (const float*)d_in[3];    // (2,128)
  const float* interp = (const float*)d_in[4];  // (5,8,40)
  float* out = (float*)d_out;                   // (6000,8,128)

  bf16_t* sig = (bf16_t*)d_ws;                                   // 61.44 MB
  bf16_t* Bt = (bf16_t*)((char*)d_ws + (size_t)N_PTS * KD * 2);  // 20.97 MB

  prep_kernel<<<SIG_BLOCKS + W2_BLOCKS, 256, 0, stream>>>(mesh, bary, kw,
                                                          interp, sig, Bt);
  gemm_kernel<<<768, 256, 0, stream>>>(sig, Bt, bias, out);
}

// Round 3
// 296.797 us; speedup vs baseline: 1.1090x; 1.0383x over previous
//
#include <hip/hip_runtime.h>
#include <hip/hip_bf16.h>

// ConvIntrinsic: gather+barycentric -> patch-operator -> 8 rotated folds.
// sig (N x 5120 bf16), W2 (2048 x 5120 bf16, interp folded into
// kernel_weights per rotation), bf16 MFMA GEMM (M=6000,N=2048,K=5120).
//
// R2: XCD swizzle; fused prep (sig+w2).
// R3: split-K x2 -> 1504 live blocks (~5.9/CU vs 2.9; latency-bound fix).
//     Partials (f32, two slots, 98.3 MB ws) + epilogue kernel doing
//     slot-sum + bias + relu + k-pair-sum. Fallback to fused single-K
//     GEMM if ws_size < 181 MB.

#define N_PTS 6000
#define RR 5
#define AA 8
#define FF 128
#define OO 128
#define QQ 40          // R*A
#define KD 5120        // QQ*FF  (GEMM K)
#define KHALF 2560
#define NCOL 2048      // 8 rot * 2 k * 128 o (GEMM N)
#define SIG_BLOCKS (N_PTS * 5)   // 5 q-chunks of 8 per point
#define W2_BLOCKS (NCOL / 2)     // 2 j per block

typedef __bf16 bf16_t;
typedef __bf16 bf16x4 __attribute__((ext_vector_type(4)));
typedef __bf16 bf16x8 __attribute__((ext_vector_type(8)));
typedef float f32x4 __attribute__((ext_vector_type(4)));

#define GLOAD_LDS16(g, l)                                              \
  __builtin_amdgcn_global_load_lds(                                    \
      (const __attribute__((address_space(1))) void*)(g),              \
      (__attribute__((address_space(3))) void*)(l), 16, 0, 0)

// ------------------------------------------------------------- prep pass
__global__ __launch_bounds__(256) void prep_kernel(
    const float* __restrict__ mesh, const float* __restrict__ bary,
    const float* __restrict__ kw, const float* __restrict__ interp,
    bf16_t* __restrict__ sig, bf16_t* __restrict__ Bt) {
  __shared__ float sI[RR * AA * QQ];  // 1600 floats (w2 branch only)
  const int bx = blockIdx.x;
  const int tid = threadIdx.x;

  if (bx < SIG_BLOCKS) {
    // ---- sig: one (n, 8-q chunk) per block; 32 lanes x float4 over f.
    const int n = bx / 5;
    const int qb = bx - n * 5;
    const int qi = tid >> 5;        // 0..7
    const int l = tid & 31;         // f = l*4
    const int q = qb * 8 + qi;
    const float* b = bary + (size_t)n * (QQ * 6) + q * 6;
    const float2 p0 = *(const float2*)(b);
    const float2 p1 = *(const float2*)(b + 2);
    const float2 p2 = *(const float2*)(b + 4);
    const int i0 = (int)p0.x; const float w0 = p0.y;
    const int i1 = (int)p1.x; const float w1 = p1.y;
    const int i2 = (int)p2.x; const float w2 = p2.y;
    const float4 v0 = *(const float4*)(mesh + (size_t)i0 * FF + l * 4);
    const float4 v1 = *(const float4*)(mesh + (size_t)i1 * FF + l * 4);
    const float4 v2 = *(const float4*)(mesh + (size_t)i2 * FF + l * 4);
    bf16x4 o;
    o[0] = (bf16_t)(w0 * v0.x + w1 * v1.x + w2 * v2.x);
    o[1] = (bf16_t)(w0 * v0.y + w1 * v1.y + w2 * v2.y);
    o[2] = (bf16_t)(w0 * v0.z + w1 * v1.z + w2 * v2.z);
    o[3] = (bf16_t)(w0 * v0.w + w1 * v1.w + w2 * v2.w);
    *(bf16x4*)(sig + (size_t)n * KD + q * FF + l * 4) = o;
  } else {
    // ---- w2: two j columns per block (128 threads each).
    const int j = (bx - SIG_BLOCKS) * 2 + (tid >> 7);
    const int f = tid & 127;
    for (int i = tid; i < RR * AA * QQ; i += 256) sI[i] = interp[i];
    __syncthreads();
    const int rot = j >> 8;
    const int o = (j >> 1) & 127;
    const int k = j & 1;
    float acc[QQ];
#pragma unroll
    for (int q = 0; q < QQ; ++q) acc[q] = 0.f;
    for (int r = 0; r < RR; ++r) {
      for (int a = 0; a < AA; ++a) {
        const int a2 = (a + rot) & 7;
        const float kv =
            kw[((size_t)((r * AA + a2) * 2 + k) * OO + o) * FF + f];
        const float4* ip = (const float4*)(sI + (r * AA + a) * QQ);
#pragma unroll
        for (int q4 = 0; q4 < QQ / 4; ++q4) {
          const float4 w4 = ip[q4];
          acc[q4 * 4 + 0] += w4.x * kv;
          acc[q4 * 4 + 1] += w4.y * kv;
          acc[q4 * 4 + 2] += w4.z * kv;
          acc[q4 * 4 + 3] += w4.w * kv;
        }
      }
    }
    bf16_t* bj = Bt + (size_t)j * KD;
#pragma unroll
    for (int q = 0; q < QQ; ++q) bj[q * FF + f] = (bf16_t)acc[q];
  }
}

// ------------------------------------------------- GEMM core (macro body)
// 128x128 tile, BK=64, 4 waves x 4x4 MFMA 16x16x32 bf16,
// global_load_lds width=16, XOR bank swizzle. Computes acc over [k_lo,k_hi).
#define GEMM_CORE(k_lo, k_hi)                                              \
  __shared__ bf16_t As[128 * 64];                                          \
  __shared__ bf16_t Bs[128 * 64];                                          \
  const int tid = threadIdx.x;                                             \
  const int wave = tid >> 6;                                               \
  const int lane = tid & 63;                                               \
  const int quad = lane >> 4;                                              \
  const int tl = lane & 15;                                                \
  const int wm = (wave & 1) * 64;                                          \
  const int wn = (wave >> 1) * 64;                                         \
  const int srow = lane >> 3;                                              \
  const int sc = (lane & 7) ^ srow;                                        \
  f32x4 acc[4][4];                                                         \
  _Pragma("unroll") for (int mm = 0; mm < 4; ++mm)                         \
      _Pragma("unroll") for (int nn = 0; nn < 4; ++nn)                     \
          acc[mm][nn] = {0.f, 0.f, 0.f, 0.f};                              \
  for (int kk = (k_lo); kk < (k_hi); kk += 64) {                           \
    __syncthreads();                                                       \
    _Pragma("unroll") for (int i = 0; i < 4; ++i) {                        \
      const int row = wave * 32 + i * 8;                                   \
      int gm = m0 + row + srow;                                            \
      gm = gm < N_PTS ? gm : (N_PTS - 1);                                  \
      const int gn = n0 + row + srow;                                      \
      GLOAD_LDS16(Asig + (size_t)gm * KD + kk + sc * 8, As + row * 64);    \
      GLOAD_LDS16(Bt + (size_t)gn * KD + kk + sc * 8, Bs + row * 64);      \
    }                                                                      \
    __syncthreads();                                                       \
    _Pragma("unroll") for (int ks = 0; ks < 2; ++ks) {                     \
      const int ch = (((ks * 4 + quad) ^ (tl & 7)) * 8);                   \
      bf16x8 af[4], bfr[4];                                                \
      _Pragma("unroll") for (int mm = 0; mm < 4; ++mm)                     \
          af[mm] = *(const bf16x8*)(As + (wm + mm * 16 + tl) * 64 + ch);   \
      _Pragma("unroll") for (int nn = 0; nn < 4; ++nn)                     \
          bfr[nn] = *(const bf16x8*)(Bs + (wn + nn * 16 + tl) * 64 + ch);  \
      _Pragma("unroll") for (int mm = 0; mm < 4; ++mm)                     \
          _Pragma("unroll") for (int nn = 0; nn < 4; ++nn)                 \
              acc[mm][nn] = __builtin_amdgcn_mfma_f32_16x16x32_bf16(       \
                  af[mm], bfr[nn], acc[mm][nn], 0, 0, 0);                  \
    }                                                                      \
  }

// ----------------------------------------------- split-K GEMM (partials)
// Grid 1536: xcd = L&7; slot = K-half; 16 n-blocks per (my,slot) share an
// A-half-tile within one XCD's L2.
__global__ __launch_bounds__(256) void gemm_split_kernel(
    const bf16_t* __restrict__ Asig, const bf16_t* __restrict__ Bt,
    float* __restrict__ Cpart) {
  const int L = blockIdx.x;
  const int xcd = L & 7;
  const int t = L >> 3;               // 0..191
  const int slot = t & 1;
  const int u = t >> 1;               // 0..95
  const int my = xcd + 8 * (u >> 4);  // 0..47
  const int nx = u & 15;
  const int m0 = my * 128;
  const int n0 = nx * 128;
  if (m0 >= N_PTS) return;

  GEMM_CORE(slot * KHALF, (slot + 1) * KHALF)

  float* cp = Cpart + (size_t)slot * N_PTS * NCOL;
#pragma unroll
  for (int nn = 0; nn < 4; ++nn) {
    const int j = n0 + wn + nn * 16 + tl;
#pragma unroll
    for (int mm = 0; mm < 4; ++mm) {
      const int mrow = m0 + wm + mm * 16 + quad * 4;
      const f32x4 a = acc[mm][nn];
#pragma unroll
      for (int r = 0; r < 4; ++r)
        if (mrow + r < N_PTS) cp[(size_t)(mrow + r) * NCOL + j] = a[r];
    }
  }
}

// --------------------------------------- epilogue: slot-sum+bias+relu+fold
// out[m, h] = relu(C[m,2h]+40*b[0,o]) + relu(C[m,2h+1]+40*b[1,o]), h=rot*128+o
__global__ __launch_bounds__(256) void epilogue_kernel(
    const float* __restrict__ Cpart, const float* __restrict__ bias,
    float* __restrict__ out) {
  const int m = blockIdx.x >> 1;
  const int half = blockIdx.x & 1;
  const int jb = half * 1024 + threadIdx.x * 4;  // j base (even)
  const float* c0 = Cpart + (size_t)m * NCOL + jb;
  const float* c1 = c0 + (size_t)N_PTS * NCOL;
  const f32x4 a0 = *(const f32x4*)c0;
  const f32x4 a1 = *(const f32x4*)c1;
  const int h0 = jb >> 1;
  const int o0 = h0 & 127, o1 = (h0 + 1) & 127;
  float s0 = a0[0] + a1[0] + 40.0f * bias[o0];
  float s1 = a0[1] + a1[1] + 40.0f * bias[128 + o0];
  float s2 = a0[2] + a1[2] + 40.0f * bias[o1];
  float s3 = a0[3] + a1[3] + 40.0f * bias[128 + o1];
  s0 = s0 > 0.f ? s0 : 0.f;
  s1 = s1 > 0.f ? s1 : 0.f;
  s2 = s2 > 0.f ? s2 : 0.f;
  s3 = s3 > 0.f ? s3 : 0.f;
  float2 v = {s0 + s1, s2 + s3};
  *(float2*)(out + (size_t)m * 1024 + h0) = v;
}

// ------------------------------------- fallback: fused single-K GEMM (R2)
__global__ __launch_bounds__(256) void gemm_fused_kernel(
    const bf16_t* __restrict__ Asig, const bf16_t* __restrict__ Bt,
    const float* __restrict__ bias, float* __restrict__ out) {
  const int L = blockIdx.x;
  const int xcd = L & 7;
  const int s = L >> 3;
  const int my = xcd + 8 * (s >> 4);
  const int nx = s & 15;
  const int m0 = my * 128;
  const int n0 = nx * 128;
  if (m0 >= N_PTS) return;

  GEMM_CORE(0, KD)

#pragma unroll
  for (int nn = 0; nn < 4; ++nn) {
    const int j = n0 + wn + nn * 16 + tl;
    const int half = j >> 1;
    const float bb = 40.0f * bias[((j & 1) << 7) | (half & 127)];
#pragma unroll
    for (int mm = 0; mm < 4; ++mm) {
      const int mrow = m0 + wm + mm * 16 + quad * 4;
      const f32x4 a = acc[mm][nn];
#pragma unroll
      for (int r = 0; r < 4; ++r) {
        float v = a[r] + bb;
        v = v > 0.f ? v : 0.f;
        const float vs = v + __shfl_xor(v, 1, 64);
        if (((lane & 1) == 0) && (mrow + r < N_PTS))
          out[(size_t)(mrow + r) * (AA * OO) + half] = vs;
      }
    }
  }
}

extern "C" void kernel_launch(void* const* d_in, const int* in_sizes, int n_in,
                              void* d_out, int out_size, void* d_ws,
                              size_t ws_size, hipStream_t stream) {
  const float* mesh = (const float*)d_in[0];    // (6000,128)
  const float* bary = (const float*)d_in[1];    // (6000,5,8,3,2)
  const float* kw = (const float*)d_in[2];      // (5,8,2,128,128)
  const float* bias = (const float*)d_in[3];    // (2,128)
  const float* interp = (const float*)d_in[4];  // (5,8,40)
  float* out = (float*)d_out;                   // (6000,8,128)

  const size_t sig_bytes = (size_t)N_PTS * KD * 2;   // 61.44 MB
  const size_t bt_bytes = (size_t)NCOL * KD * 2;     // 20.97 MB
  const size_t cp_bytes = (size_t)2 * N_PTS * NCOL * 4;  // 98.30 MB

  bf16_t* sig = (bf16_t*)d_ws;
  bf16_t* Bt = (bf16_t*)((char*)d_ws + sig_bytes);
  float* Cpart = (float*)((char*)d_ws + sig_bytes + bt_bytes);

  prep_kernel<<<SIG_BLOCKS + W2_BLOCKS, 256, 0, stream>>>(mesh, bary, kw,
                                                          interp, sig, Bt);
  if (ws_size >= sig_bytes + bt_bytes + cp_bytes) {
    gemm_split_kernel<<<1536, 256, 0, stream>>>(sig, Bt, Cpart);
    epilogue_kernel<<<N_PTS * 2, 256, 0, stream>>>(Cpart, bias, out);
  } else {
    gemm_fused_kernel<<<768, 256, 0, stream>>>(sig, Bt, bias, out);
  }
}

// Round 4
// 269.165 us; speedup vs baseline: 1.2228x; 1.1027x over previous
//
#include <hip/hip_runtime.h>
#include <hip/hip_bf16.h>

// ConvIntrinsic: gather+barycentric -> patch-operator -> 8 rotated folds.
// R4 key identity: interp[r,a,(rho,alpha)] depends only on (a-alpha)&7
// (Gaussian of polar distance), so W2_rot[(rho,alpha)] = W2_0[(rho,alpha+rot)]:
// all 8 rotations share ONE 256-column B (2.6 MB, L2-resident); the roll is a
// scalar q-permute on A's k-offset. GEMM: virtualM=(rot,n)=8x6000, N=256,
// K=5120 bf16 MFMA, split-K x2 (1536 blocks), XCD-swizzled so one sig slab +
// whole B fit one XCD's 4MB L2. w2 prep shrinks 8x (was ~30us of LDS pipe).

#define N_PTS 6000
#define MROWS 6016     // padded rows per rot in partial buffer
#define RR 5
#define AA 8
#define FF 128
#define OO 128
#define QQ 40          // R*A
#define KD 5120        // QQ*FF  (GEMM K)
#define KHALF 2560
#define NCOL 256       // 2 k * 128 o (GEMM N, single-rot B)
#define SIG_BLOCKS (N_PTS * 5)   // 5 q-chunks of 8 per point
#define W2_BLOCKS (NCOL / 2)     // 2 j per block

typedef __bf16 bf16_t;
typedef __bf16 bf16x4 __attribute__((ext_vector_type(4)));
typedef __bf16 bf16x8 __attribute__((ext_vector_type(8)));
typedef float f32x4 __attribute__((ext_vector_type(4)));

#define GLOAD_LDS16(g, l)                                              \
  __builtin_amdgcn_global_load_lds(                                    \
      (const __attribute__((address_space(1))) void*)(g),              \
      (__attribute__((address_space(3))) void*)(l), 16, 0, 0)

// ------------------------------------------------------------- prep pass
__global__ __launch_bounds__(256) void prep_kernel(
    const float* __restrict__ mesh, const float* __restrict__ bary,
    const float* __restrict__ kw, const float* __restrict__ interp,
    bf16_t* __restrict__ sig, bf16_t* __restrict__ Bt) {
  __shared__ float sI[RR * AA * QQ];  // 1600 floats (w2 branch only)
  const int bx = blockIdx.x;
  const int tid = threadIdx.x;

  if (bx < SIG_BLOCKS) {
    // ---- sig: one (n, 8-q chunk) per block; 32 lanes x float4 over f.
    const int n = bx / 5;
    const int qb = bx - n * 5;
    const int qi = tid >> 5;        // 0..7
    const int l = tid & 31;         // f = l*4
    const int q = qb * 8 + qi;
    const float* b = bary + (size_t)n * (QQ * 6) + q * 6;
    const float2 p0 = *(const float2*)(b);
    const float2 p1 = *(const float2*)(b + 2);
    const float2 p2 = *(const float2*)(b + 4);
    const int i0 = (int)p0.x; const float w0 = p0.y;
    const int i1 = (int)p1.x; const float w1 = p1.y;
    const int i2 = (int)p2.x; const float w2 = p2.y;
    const float4 v0 = *(const float4*)(mesh + (size_t)i0 * FF + l * 4);
    const float4 v1 = *(const float4*)(mesh + (size_t)i1 * FF + l * 4);
    const float4 v2 = *(const float4*)(mesh + (size_t)i2 * FF + l * 4);
    bf16x4 o;
    o[0] = (bf16_t)(w0 * v0.x + w1 * v1.x + w2 * v2.x);
    o[1] = (bf16_t)(w0 * v0.y + w1 * v1.y + w2 * v2.y);
    o[2] = (bf16_t)(w0 * v0.z + w1 * v1.z + w2 * v2.z);
    o[3] = (bf16_t)(w0 * v0.w + w1 * v1.w + w2 * v2.w);
    *(bf16x4*)(sig + (size_t)n * KD + q * FF + l * 4) = o;
  } else {
    // ---- w2 (rot=0 only): two j columns per block (128 threads each).
    const int j = (bx - SIG_BLOCKS) * 2 + (tid >> 7);  // 0..255
    const int f = tid & 127;
    for (int i = tid; i < RR * AA * QQ; i += 256) sI[i] = interp[i];
    __syncthreads();
    const int o = (j >> 1) & 127;
    const int k = j & 1;
    float acc[QQ];
#pragma unroll
    for (int q = 0; q < QQ; ++q) acc[q] = 0.f;
    for (int r = 0; r < RR; ++r) {
      for (int a = 0; a < AA; ++a) {
        const float kv =
            kw[((size_t)((r * AA + a) * 2 + k) * OO + o) * FF + f];
        const float4* ip = (const float4*)(sI + (r * AA + a) * QQ);
#pragma unroll
        for (int q4 = 0; q4 < QQ / 4; ++q4) {
          const float4 w4 = ip[q4];
          acc[q4 * 4 + 0] += w4.x * kv;
          acc[q4 * 4 + 1] += w4.y * kv;
          acc[q4 * 4 + 2] += w4.z * kv;
          acc[q4 * 4 + 3] += w4.w * kv;
        }
      }
    }
    bf16_t* bj = Bt + (size_t)j * KD;
#pragma unroll
    for (int q = 0; q < QQ; ++q) bj[q * FF + f] = (bf16_t)acc[q];
  }
}

// ------------------------------------------------- GEMM core (macro body)
// 128x128 tile, BK=64, 4 waves x 4x4 MFMA 16x16x32 bf16, global_load_lds
// width=16, XOR bank swizzle. A k-offset gets the wave-uniform rot-permute:
// q_src = (q & 56) | ((q - rot) & 7)   (BK=64 never straddles a q block).
#define GEMM_CORE(k_lo, k_hi)                                              \
  __shared__ bf16_t As[128 * 64];                                          \
  __shared__ bf16_t Bs[128 * 64];                                          \
  const int tid = threadIdx.x;                                             \
  const int wave = tid >> 6;                                               \
  const int lane = tid & 63;                                               \
  const int quad = lane >> 4;                                              \
  const int tl = lane & 15;                                                \
  const int wm = (wave & 1) * 64;                                          \
  const int wn = (wave >> 1) * 64;                                         \
  const int srow = lane >> 3;                                              \
  const int sc = (lane & 7) ^ srow;                                        \
  f32x4 acc[4][4];                                                         \
  _Pragma("unroll") for (int mm = 0; mm < 4; ++mm)                         \
      _Pragma("unroll") for (int nn = 0; nn < 4; ++nn)                     \
          acc[mm][nn] = {0.f, 0.f, 0.f, 0.f};                              \
  for (int kk = (k_lo); kk < (k_hi); kk += 64) {                           \
    const int qq = kk >> 7;                                                \
    const int akk = (((qq & 56) | ((qq - rot) & 7)) << 7) | (kk & 127);    \
    __syncthreads();                                                       \
    _Pragma("unroll") for (int i = 0; i < 4; ++i) {                        \
      const int row = wave * 32 + i * 8;                                   \
      int gm = m0 + row + srow;                                            \
      gm = gm < N_PTS ? gm : (N_PTS - 1);                                  \
      const int gn = n0 + row + srow;                                      \
      GLOAD_LDS16(Asig + (size_t)gm * KD + akk + sc * 8, As + row * 64);   \
      GLOAD_LDS16(Bt + (size_t)gn * KD + kk + sc * 8, Bs + row * 64);      \
    }                                                                      \
    __syncthreads();                                                       \
    _Pragma("unroll") for (int ks = 0; ks < 2; ++ks) {                     \
      const int ch = (((ks * 4 + quad) ^ (tl & 7)) * 8);                   \
      bf16x8 af[4], bfr[4];                                                \
      _Pragma("unroll") for (int mm = 0; mm < 4; ++mm)                     \
          af[mm] = *(const bf16x8*)(As + (wm + mm * 16 + tl) * 64 + ch);   \
      _Pragma("unroll") for (int nn = 0; nn < 4; ++nn)                     \
          bfr[nn] = *(const bf16x8*)(Bs + (wn + nn * 16 + tl) * 64 + ch);  \
      _Pragma("unroll") for (int mm = 0; mm < 4; ++mm)                     \
          _Pragma("unroll") for (int nn = 0; nn < 4; ++nn)                 \
              acc[mm][nn] = __builtin_amdgcn_mfma_f32_16x16x32_bf16(       \
                  af[mm], bfr[nn], acc[mm][nn], 0, 0, 0);                  \
    }                                                                      \
  }

// ----------------------------------------------- split-K GEMM (partials)
// Grid 1536: xcd=L&7, t=L>>3 (0..191); slab g = xcd+8*(t>>5) (same 128 sig
// rows for all 32 inner blocks: 8 rot x 2 ncol x 2 slot -> one XCD's L2;
// B (2.6 MB) is L2-resident everywhere).
__global__ __launch_bounds__(256) void gemm_split_kernel(
    const bf16_t* __restrict__ Asig, const bf16_t* __restrict__ Bt,
    float* __restrict__ Cpart) {
  const int L = blockIdx.x;
  const int xcd = L & 7;
  const int t = L >> 3;                // 0..191
  const int g = xcd + 8 * (t >> 5);    // 0..47 sig slab
  const int inner = t & 31;
  const int rot = inner & 7;
  const int n0 = ((inner >> 3) & 1) * 128;
  const int slot = inner >> 4;
  const int m0 = g * 128;
  if (m0 >= N_PTS) return;

  GEMM_CORE(slot * KHALF, (slot + 1) * KHALF)

  float* cp = Cpart + ((size_t)(slot * 8 + rot) * MROWS) * NCOL;
#pragma unroll
  for (int nn = 0; nn < 4; ++nn) {
    const int j = n0 + wn + nn * 16 + tl;
#pragma unroll
    for (int mm = 0; mm < 4; ++mm) {
      const int mrow = m0 + wm + mm * 16 + quad * 4;
      const f32x4 a = acc[mm][nn];
#pragma unroll
      for (int r = 0; r < 4; ++r)
        cp[(size_t)(mrow + r) * NCOL + j] = a[r];  // rows >=6000 = scratch
    }
  }
}

// --------------------------------------- epilogue: slot-sum+bias+relu+fold
// out[m, rot*128+o] = relu(C[2o]+40*b[0,o]) + relu(C[2o+1]+40*b[1,o])
__global__ __launch_bounds__(256) void epilogue_kernel(
    const float* __restrict__ Cpart, const float* __restrict__ bias,
    float* __restrict__ out) {
  const int m = blockIdx.x;
  const int rot = threadIdx.x >> 5;
  const int o0 = (threadIdx.x & 31) * 4;
  const size_t base = ((size_t)rot * MROWS + m) * NCOL + o0 * 2;
  const size_t slot_stride = (size_t)8 * MROWS * NCOL;
  const f32x4 a0 = *(const f32x4*)(Cpart + base);
  const f32x4 a1 = *(const f32x4*)(Cpart + base + 4);
  const f32x4 b0 = *(const f32x4*)(Cpart + slot_stride + base);
  const f32x4 b1 = *(const f32x4*)(Cpart + slot_stride + base + 4);
  f32x4 r;
#pragma unroll
  for (int i = 0; i < 2; ++i) {
    const int o = o0 + i;
    float sk0 = a0[2 * i] + b0[2 * i] + 40.0f * bias[o];
    float sk1 = a0[2 * i + 1] + b0[2 * i + 1] + 40.0f * bias[128 + o];
    sk0 = sk0 > 0.f ? sk0 : 0.f;
    sk1 = sk1 > 0.f ? sk1 : 0.f;
    r[i] = sk0 + sk1;
  }
#pragma unroll
  for (int i = 0; i < 2; ++i) {
    const int o = o0 + 2 + i;
    float sk0 = a1[2 * i] + b1[2 * i] + 40.0f * bias[o];
    float sk1 = a1[2 * i + 1] + b1[2 * i + 1] + 40.0f * bias[128 + o];
    sk0 = sk0 > 0.f ? sk0 : 0.f;
    sk1 = sk1 > 0.f ? sk1 : 0.f;
    r[2 + i] = sk0 + sk1;
  }
  *(f32x4*)(out + (size_t)m * 1024 + rot * 128 + o0) = r;
}

// ------------------------------------- fallback: fused single-K GEMM
__global__ __launch_bounds__(256) void gemm_fused_kernel(
    const bf16_t* __restrict__ Asig, const bf16_t* __restrict__ Bt,
    const float* __restrict__ bias, float* __restrict__ out) {
  const int L = blockIdx.x;
  const int xcd = L & 7;
  const int t = L >> 3;                // 0..95
  const int g = xcd + 8 * (t >> 4);    // 0..47
  const int inner = t & 15;
  const int rot = inner & 7;
  const int n0 = (inner >> 3) * 128;
  const int m0 = g * 128;
  if (m0 >= N_PTS) return;

  GEMM_CORE(0, KD)

#pragma unroll
  for (int nn = 0; nn < 4; ++nn) {
    const int j = n0 + wn + nn * 16 + tl;  // 0..255
    const float bb = 40.0f * bias[((j & 1) << 7) | (j >> 1)];
#pragma unroll
    for (int mm = 0; mm < 4; ++mm) {
      const int mrow = m0 + wm + mm * 16 + quad * 4;
      const f32x4 a = acc[mm][nn];
#pragma unroll
      for (int r = 0; r < 4; ++r) {
        float v = a[r] + bb;
        v = v > 0.f ? v : 0.f;
        const float vs = v + __shfl_xor(v, 1, 64);
        if (((lane & 1) == 0) && (mrow + r < N_PTS))
          out[(size_t)(mrow + r) * 1024 + rot * 128 + (j >> 1)] = vs;
      }
    }
  }
}

extern "C" void kernel_launch(void* const* d_in, const int* in_sizes, int n_in,
                              void* d_out, int out_size, void* d_ws,
                              size_t ws_size, hipStream_t stream) {
  const float* mesh = (const float*)d_in[0];    // (6000,128)
  const float* bary = (const float*)d_in[1];    // (6000,5,8,3,2)
  const float* kw = (const float*)d_in[2];      // (5,8,2,128,128)
  const float* bias = (const float*)d_in[3];    // (2,128)
  const float* interp = (const float*)d_in[4];  // (5,8,40)
  float* out = (float*)d_out;                   // (6000,8,128)

  const size_t sig_bytes = (size_t)N_PTS * KD * 2;            // 61.44 MB
  const size_t bt_bytes = (size_t)NCOL * KD * 2;              // 2.62 MB
  const size_t cp_bytes = (size_t)2 * 8 * MROWS * NCOL * 4;   // 98.57 MB

  bf16_t* sig = (bf16_t*)d_ws;
  bf16_t* Bt = (bf16_t*)((char*)d_ws + sig_bytes);
  float* Cpart = (float*)((char*)d_ws + sig_bytes + bt_bytes);

  prep_kernel<<<SIG_BLOCKS + W2_BLOCKS, 256, 0, stream>>>(mesh, bary, kw,
                                                          interp, sig, Bt);
  if (ws_size >= sig_bytes + bt_bytes + cp_bytes) {
    gemm_split_kernel<<<1536, 256, 0, stream>>>(sig, Bt, Cpart);
    epilogue_kernel<<<N_PTS, 256, 0, stream>>>(Cpart, bias, out);
  } else {
    gemm_fused_kernel<<<768, 256, 0, stream>>>(sig, Bt, bias, out);
  }
}